// Round 4
// baseline (368.514 us; speedup 1.0000x reference)
//
#include <hip/hip_runtime.h>
#include <cstdint>

typedef __bf16 bf16;
typedef __attribute__((ext_vector_type(8))) __bf16 bf16x8;
typedef __attribute__((ext_vector_type(4))) __bf16 bf16x4;
typedef __attribute__((ext_vector_type(4))) float f32x4;

__device__ __forceinline__ void load_lds16(const void* g, void* l) {
  __builtin_amdgcn_global_load_lds(
      (const __attribute__((address_space(1))) unsigned int*)g,
      (__attribute__((address_space(3))) unsigned int*)l, 16, 0, 0);
}

__device__ __forceinline__ float fast_exp2(float x) {
  float r;
  asm volatile("v_exp_f32 %0, %1" : "=v"(r) : "v"(x));
  return r;
}

// ---------------------------------------------------------------------------
// GEMM: C[M,N] = A[M,K] @ Bt[N,K]^T (+bias). 128x128 tile, BK=64, 256 thr.
// ---------------------------------------------------------------------------
template <bool OUT_F32>
__global__ __launch_bounds__(256) void gemm_bt(
    const bf16* __restrict__ A, const bf16* __restrict__ Bt,
    const float* __restrict__ bias, void* __restrict__ Cv,
    int M, int N, int K) {
  __shared__ __align__(16) bf16 sA[128 * 64];
  __shared__ __align__(16) bf16 sB[128 * 64];
  const int t = threadIdx.x;
  const int w = t >> 6, lane = t & 63;
  const int quad = lane >> 4, l16 = lane & 15;
  const int wm = (w >> 1) * 64, wn = (w & 1) * 64;
  const int bm = blockIdx.y * 128, bn = blockIdx.x * 128;

  f32x4 acc[4][4] = {};
  const int srow = lane >> 3;
  const int sg = lane & 7;

  for (int kt = 0; kt < (K >> 6); ++kt) {
    const int k0 = kt << 6;
#pragma unroll
    for (int c2 = 0; c2 < 4; ++c2) {
      int c = c2 * 4 + w;
      int row = c * 8 + srow;
      int gg = sg ^ (row & 7);
      load_lds16(A + (int64_t)(bm + row) * K + k0 + gg * 8, sA + c * 512);
      load_lds16(Bt + (int64_t)(bn + row) * K + k0 + gg * 8, sB + c * 512);
    }
    asm volatile("s_waitcnt vmcnt(0)" ::: "memory");
    __syncthreads();
#pragma unroll
    for (int ks = 0; ks < 2; ++ks) {
      bf16x8 af[4], bfr[4];
#pragma unroll
      for (int i = 0; i < 4; ++i) {
        int m = wm + i * 16 + l16;
        af[i] = *(const bf16x8*)(sA + m * 64 + (((ks * 4 + quad) ^ (l16 & 7)) * 8));
        int n = wn + i * 16 + l16;
        bfr[i] = *(const bf16x8*)(sB + n * 64 + (((ks * 4 + quad) ^ (l16 & 7)) * 8));
      }
#pragma unroll
      for (int i = 0; i < 4; ++i)
#pragma unroll
        for (int j = 0; j < 4; ++j)
          acc[i][j] = __builtin_amdgcn_mfma_f32_16x16x32_bf16(af[i], bfr[j],
                                                              acc[i][j], 0, 0, 0);
    }
    __syncthreads();
  }
#pragma unroll
  for (int i = 0; i < 4; ++i) {
    int gm = bm + wm + i * 16 + quad * 4;
#pragma unroll
    for (int j = 0; j < 4; ++j) {
      int gn = bn + wn + j * 16 + l16;
      float bvv = bias ? bias[gn] : 0.0f;
#pragma unroll
      for (int r = 0; r < 4; ++r) {
        float v = acc[i][j][r] + bvv;
        if (OUT_F32)
          ((float*)Cv)[(int64_t)(gm + r) * N + gn] = v;
        else
          ((bf16*)Cv)[(int64_t)(gm + r) * N + gn] = (bf16)v;
      }
    }
  }
}

// ---------------------------------------------------------------------------
// Flash attention, split-kv(2) x mirror-paired q-tiles, kv tiles of 32.
// Block = 4 waves; tiles A=p, B=31-p (64 q rows each); wave owns 16 q of each.
// z = kv-split half. Each block: 33 compute-tiles. Partial O (unnormalized,
// bf16) + per-q (m,l) f32 written for a later combine kernel.
// S^T = K Q^T (in-lane softmax), O^T = V^T P^T.  LDS: 16+16+8 = 40 KiB.
// ---------------------------------------------------------------------------
__global__ __launch_bounds__(256, 3) void attn(
    const bf16* __restrict__ QKV, const bf16* __restrict__ Vt,
    bf16* __restrict__ O1, bf16* __restrict__ O2,
    float* __restrict__ m_arr, float* __restrict__ l_arr) {
  constexpr float CC = 0.08838834764831845f * 1.44269504088896f;  // scale*log2e
  __shared__ __align__(16) bf16 sK[2][32 * 128];  // [kv][k-granules] 8 KB x2
  __shared__ __align__(16) bf16 sV[2][128 * 32];  // [d][kv]          8 KB x2
  __shared__ __align__(16) bf16 sP[128 * 32];     // [q_local][kv]    8 KB

  const int t = threadIdx.x;
  const int w = t >> 6, lane = t & 63;
  const int quad = lane >> 4, l16 = lane & 15;
  const int p = blockIdx.x, h = blockIdx.y;
  const int b = blockIdx.z >> 1, z = blockIdx.z & 1;
  const int g = h >> 2;
  const int wr0 = w * 16;
  const int kbase = 2048 + g * 128;
  const bf16* vtb = Vt + (int64_t)((b * 4 + g) * 128) * 2048;
  const int qrow0A = p * 64, qrow0B = (31 - p) * 64;
  const int NV = (z == 0) ? (32 - p) : 33;

  // vi -> (kv tile, active flags)
  auto map = [&](int vi, int& tl, bool& aA, bool& aB) {
    if (z == 0) { tl = vi; aA = (vi <= p); aB = true; }
    else if (vi <= p) { tl = p + 1 + vi; aA = true; aB = false; }
    else { tl = 31 - 2 * p + vi; aA = false; aB = true; }
  };

  // Q fragments (B-operand of S^T = K Q^T), registers for whole kernel
  bf16x8 qreg[2][4];
#pragma unroll
  for (int u = 0; u < 2; ++u) {
    int qr = (u == 0 ? qrow0A : qrow0B);
#pragma unroll
    for (int ks = 0; ks < 4; ++ks)
      qreg[u][ks] = *(const bf16x8*)(QKV +
          (int64_t)(b * 2048 + qr + wr0 + l16) * 3072 + h * 128 + ks * 32 +
          quad * 8);
  }

  f32x4 oacc[2][8] = {};
  float mrow[2] = {-3.0e38f, -3.0e38f};
  float lrow[2] = {0.f, 0.f};

  const int rk = lane >> 4;            // K: 4 rows per 1KB chunk
  const int rv = lane >> 2, gv = lane & 3;  // V: 16 rows per 1KB chunk

  auto stage = [&](int tl, int buf) {
    int n0 = tl * 32;
#pragma unroll
    for (int r = 0; r < 2; ++r) {
      int c = r * 4 + w;  // chunk 0..7
      int rowk = c * 4 + rk;                      // kv row 0..31
      int ggk = (l16 & 8) | ((l16 ^ rowk) & 7);   // global k-granule
      load_lds16(QKV + (int64_t)(b * 2048 + n0 + rowk) * 3072 + kbase + ggk * 8,
                 sK[buf] + c * 512);
      int rowv = c * 16 + rv;                     // d row 0..127
      int ggv = gv ^ (rowv & 3);                  // global kv-granule
      load_lds16(vtb + (int64_t)rowv * 2048 + n0 + ggv * 8, sV[buf] + c * 512);
    }
  };

  {
    int tl0; bool a0, b0;
    map(0, tl0, a0, b0);
    stage(tl0, 0);
  }

  const int prowA = wr0 + l16;        // sP row, tile A (0..63)
  const int prowB = 64 + wr0 + l16;   // tile B (64..127)

  for (int vi = 0; vi < NV; ++vi) {
    const int cur = vi & 1;
    int tl; bool actA, actB;
    map(vi, tl, actA, actB);
    const int n0 = tl * 32;
    bf16* sKc = sK[cur];
    bf16* sVc = sV[cur];

    asm volatile("s_waitcnt vmcnt(0)\n\ts_barrier" ::: "memory");
    if (vi + 1 < NV) {
      int tln; bool an, bn_;
      map(vi + 1, tln, an, bn_);
      stage(tln, cur ^ 1);
    }

    // ---- S^T = K Q^T : rows kv = mj*16+quad*4+r, col q = l16 ----
    f32x4 sacc[2][2] = {};
#pragma unroll
    for (int ks = 0; ks < 4; ++ks) {
      bf16x8 ak[2];
#pragma unroll
      for (int mj = 0; mj < 2; ++mj) {
        int kvr = mj * 16 + l16;
        int G = ks * 4 + quad;
        int slot = (G & 8) | ((G ^ kvr) & 7);
        ak[mj] = *(const bf16x8*)(sKc + kvr * 128 + slot * 8);
      }
      if (actA)
#pragma unroll
        for (int mj = 0; mj < 2; ++mj)
          sacc[0][mj] = __builtin_amdgcn_mfma_f32_16x16x32_bf16(
              ak[mj], qreg[0][ks], sacc[0][mj], 0, 0, 0);
      if (actB)
#pragma unroll
        for (int mj = 0; mj < 2; ++mj)
          sacc[1][mj] = __builtin_amdgcn_mfma_f32_16x16x32_bf16(
              ak[mj], qreg[1][ks], sacc[1][mj], 0, 0, 0);
    }

    // ---- online softmax (raw scores, scale in CC) + P^T write ----
    auto softmax_u = [&](int u, int qrow0u, int prow) {
      if (n0 + 31 > qrow0u + wr0) {
        int q = qrow0u + wr0 + l16;
#pragma unroll
        for (int mj = 0; mj < 2; ++mj)
#pragma unroll
          for (int r = 0; r < 4; ++r) {
            int kv = n0 + mj * 16 + quad * 4 + r;
            if (kv > q) sacc[u][mj][r] = -3.0e38f;
          }
      }
      f32x4 m01;
#pragma unroll
      for (int r = 0; r < 4; ++r) m01[r] = fmaxf(sacc[u][0][r], sacc[u][1][r]);
      float mx = fmaxf(fmaxf(m01[0], m01[1]), fmaxf(m01[2], m01[3]));
      mx = fmaxf(mx, __shfl_xor(mx, 16));
      mx = fmaxf(mx, __shfl_xor(mx, 32));
      float mnew = fmaxf(mrow[u], mx);
      float alpha = fast_exp2((mrow[u] - mnew) * CC);
      float rs = 0.f;
#pragma unroll
      for (int mj = 0; mj < 2; ++mj) {
        bf16x4 p4;
#pragma unroll
        for (int r = 0; r < 4; ++r) {
          float pv = fast_exp2((sacc[u][mj][r] - mnew) * CC);
          rs += pv;
          p4[r] = (bf16)pv;
        }
        int g16 = mj * 2 + (quad >> 1);
        int off = prow * 32 + ((g16 ^ (prow & 3)) * 8) + (quad & 1) * 4;
        *(bf16x4*)(sP + off) = p4;
      }
      rs += __shfl_xor(rs, 16);
      rs += __shfl_xor(rs, 32);
      lrow[u] = lrow[u] * alpha + rs;
      mrow[u] = mnew;
#pragma unroll
      for (int dj = 0; dj < 8; ++dj)
#pragma unroll
        for (int r = 0; r < 4; ++r) oacc[u][dj][r] *= alpha;
    };
    if (actA) softmax_u(0, qrow0A, prowA);
    if (actB) softmax_u(1, qrow0B, prowB);

    // own P^T writes visible to own reads (wave-private rows)
    asm volatile("s_waitcnt lgkmcnt(0)" ::: "memory");

    // ---- O^T += V^T P^T : single k-slice (kv=32) ----
    bf16x8 bpA, bpB;
    if (actA) bpA = *(const bf16x8*)(sP + prowA * 32 + ((quad ^ (prowA & 3)) * 8));
    if (actB) bpB = *(const bf16x8*)(sP + prowB * 32 + ((quad ^ (prowB & 3)) * 8));
#pragma unroll
    for (int dj = 0; dj < 8; ++dj) {
      int d = dj * 16 + l16;
      bf16x8 av = *(const bf16x8*)(sVc + d * 32 + ((quad ^ (d & 3)) * 8));
      if (actA)
        oacc[0][dj] = __builtin_amdgcn_mfma_f32_16x16x32_bf16(av, bpA,
                                                             oacc[0][dj], 0, 0, 0);
      if (actB)
        oacc[1][dj] = __builtin_amdgcn_mfma_f32_16x16x32_bf16(av, bpB,
                                                             oacc[1][dj], 0, 0, 0);
    }
  }

  // ---- epilogue: unnormalized partial O + (m,l) ----
  bf16* OutP = (z == 0) ? O1 : O2;
#pragma unroll
  for (int u = 0; u < 2; ++u) {
    int qrow0u = (u == 0 ? qrow0A : qrow0B);
    int64_t grow = b * 2048 + qrow0u + wr0 + l16;
#pragma unroll
    for (int dj = 0; dj < 8; ++dj) {
      bf16x4 o4;
#pragma unroll
      for (int r = 0; r < 4; ++r) o4[r] = (bf16)oacc[u][dj][r];
      *(bf16x4*)(OutP + grow * 2048 + h * 128 + dj * 16 + quad * 4) = o4;
    }
    if (quad == 0) {
      int mi = ((z * 2 + b) * 16 + h) * 2048 + qrow0u + wr0 + l16;
      m_arr[mi] = mrow[u];
      l_arr[mi] = lrow[u];
    }
  }
}

// ---------------------------------------------------------------------------
// Combine the two kv-split halves:
// out = (e1*O1 + e2*O2) / (e1*l1 + e2*l2),  ei = exp2((mi - max)*CC)
// ---------------------------------------------------------------------------
__global__ __launch_bounds__(256) void combine(
    const bf16* __restrict__ O1, const bf16* __restrict__ O2,
    const float* __restrict__ m_arr, const float* __restrict__ l_arr,
    bf16* __restrict__ out) {
  constexpr float CC = 0.08838834764831845f * 1.44269504088896f;
  int idx = blockIdx.x * 256 + threadIdx.x;  // 1M threads
  int dc = idx & 15;
  int h = (idx >> 4) & 15;
  int row = idx >> 8;  // b*2048+q
  int b = row >> 11, q = row & 2047;
  int mi1 = ((0 * 2 + b) * 16 + h) * 2048 + q;
  int mi2 = ((1 * 2 + b) * 16 + h) * 2048 + q;
  float m1 = m_arr[mi1], l1 = l_arr[mi1];
  float m2 = m_arr[mi2], l2 = l_arr[mi2];
  float mM = fmaxf(m1, m2);
  float e1 = fast_exp2((m1 - mM) * CC);
  float e2 = fast_exp2((m2 - mM) * CC);
  float inv = 1.0f / (e1 * l1 + e2 * l2);
  int64_t off = (int64_t)row * 2048 + h * 128 + dc * 8;
  bf16x8 o1 = *(const bf16x8*)(O1 + off);
  bf16x8 o2 = *(const bf16x8*)(O2 + off);
  bf16x8 o;
#pragma unroll
  for (int e = 0; e < 8; ++e)
    o[e] = (bf16)(((float)o1[e] * e1 + (float)o2[e] * e2) * inv);
  *(bf16x8*)(out + off) = o;
}

// ---------------------------------------------------------------------------
// Helpers
// ---------------------------------------------------------------------------
__global__ void convert_x(const float* __restrict__ x, bf16* __restrict__ xb) {
  int idx = blockIdx.x * 256 + threadIdx.x;
  float4 v = ((const float4*)x)[idx];
  bf16x4 o = {(bf16)v.x, (bf16)v.y, (bf16)v.z, (bf16)v.w};
  ((bf16x4*)xb)[idx] = o;
}

// W [K][N] fp32 -> Wt [N][K] bf16. 64x64 tiles, block (64,4)
__global__ void transpose_w(const float* __restrict__ W, bf16* __restrict__ Wt,
                            int K, int N) {
  __shared__ float tile[64][65];
  int bx = blockIdx.x, by = blockIdx.y;
  int tx = threadIdx.x, ty = threadIdx.y;
#pragma unroll
  for (int q2 = 0; q2 < 16; ++q2) {
    int r = ty + q2 * 4;
    tile[r][tx] = W[(int64_t)(by * 64 + r) * N + bx * 64 + tx];
  }
  __syncthreads();
#pragma unroll
  for (int q2 = 0; q2 < 16; ++q2) {
    int n = ty + q2 * 4;
    Wt[(int64_t)(bx * 64 + n) * K + by * 64 + tx] = (bf16)tile[tx][n];
  }
}

// V cols of QKV -> Vt [(b*4+g)*128 + d][2048]. grid (4, 64, 8), block (32,8)
__global__ void transpose_v(const bf16* __restrict__ QKV, bf16* __restrict__ Vt) {
  __shared__ bf16 tile[32][34];
  int dt = blockIdx.x, tt = blockIdx.y, bg = blockIdx.z;
  int b = bg >> 2, g = bg & 3;
  int tx = threadIdx.x, ty = threadIdx.y;
#pragma unroll
  for (int q2 = 0; q2 < 4; ++q2) {
    int trow = tt * 32 + ty + q2 * 8;
    tile[ty + q2 * 8][tx] =
        QKV[(int64_t)(b * 2048 + trow) * 3072 + 2560 + g * 128 + dt * 32 + tx];
  }
  __syncthreads();
#pragma unroll
  for (int q2 = 0; q2 < 4; ++q2) {
    int d = dt * 32 + ty + q2 * 8;
    Vt[(int64_t)(bg * 128 + d) * 2048 + tt * 32 + tx] = tile[tx][ty + q2 * 8];
  }
}

__global__ void concat_bias(const float* __restrict__ bq,
                            const float* __restrict__ bk,
                            const float* __restrict__ bv,
                            float* __restrict__ o) {
  int i = blockIdx.x * 256 + threadIdx.x;
  if (i < 3072)
    o[i] = i < 2048 ? bq[i] : (i < 2560 ? bk[i - 2048] : bv[i - 2560]);
}

// ---------------------------------------------------------------------------
extern "C" void kernel_launch(void* const* d_in, const int* in_sizes, int n_in,
                              void* d_out, int out_size, void* d_ws,
                              size_t ws_size, hipStream_t stream) {
  const float* x = (const float*)d_in[0];
  const float* Wq = (const float*)d_in[1];
  const float* bq = (const float*)d_in[2];
  const float* Wk = (const float*)d_in[3];
  const float* bk = (const float*)d_in[4];
  const float* Wv = (const float*)d_in[5];
  const float* bv = (const float*)d_in[6];
  const float* Wo = (const float*)d_in[7];
  const float* bo = (const float*)d_in[8];
  float* out = (float*)d_out;

  char* ws = (char*)d_ws;
  bf16* xb = (bf16*)(ws);                    // 16.78 MB; dead after gemm1
  bf16* wqkvT = (bf16*)(ws + 16777216);      // 12.58 MB; dead after gemm1
  bf16* woT = (bf16*)(ws + 29360128);        // 8.39 MB
  float* bqkv = (float*)(ws + 37748736);     // 12 KB
  bf16* qkv = (bf16*)(ws + 37761024);        // 25.17 MB; dead after attn
  bf16* vt = (bf16*)(ws + 62926848);         // 4.19 MB
  bf16* attnO1 = (bf16*)(ws + 67121152);     // 16.78 MB
  // overlays (regions dead by the time these are written):
  bf16* attnO2 = (bf16*)(ws);                          // over xb
  float* m_arr = (float*)(ws + 16777216);              // over wqkvT (512 KB)
  float* l_arr = (float*)(ws + 16777216 + 524288);     // (512 KB)
  bf16* attnb = (bf16*)(ws + 37761024);                // over qkv (16.78 MB)

  convert_x<<<8192, 256, 0, stream>>>(x, xb);
  dim3 tb(64, 4);
  transpose_w<<<dim3(32, 32), tb, 0, stream>>>(Wq, wqkvT, 2048, 2048);
  transpose_w<<<dim3(8, 32), tb, 0, stream>>>(Wk, wqkvT + 2048 * 2048, 2048, 512);
  transpose_w<<<dim3(8, 32), tb, 0, stream>>>(Wv, wqkvT + 2560 * 2048, 2048, 512);
  transpose_w<<<dim3(32, 32), tb, 0, stream>>>(Wo, woT, 2048, 2048);
  concat_bias<<<12, 256, 0, stream>>>(bq, bk, bv, bqkv);

  // QKV = xb @ WqkvT^T + bqkv   [4096 x 3072]
  gemm_bt<false><<<dim3(24, 32), 256, 0, stream>>>(xb, wqkvT, bqkv, qkv, 4096,
                                                   3072, 2048);
  transpose_v<<<dim3(4, 64, 8), dim3(32, 8), 0, stream>>>(qkv, vt);
  // split-kv flash attention: grid (pair p, head, b*2+z)
  attn<<<dim3(16, 16, 4), 256, 0, stream>>>(qkv, vt, attnO1, attnO2, m_arr,
                                            l_arr);
  combine<<<4096, 256, 0, stream>>>(attnO1, attnO2, m_arr, l_arr, attnb);
  // out = attnb @ WoT^T + bo    [4096 x 2048] fp32
  gemm_bt<true><<<dim3(16, 32), 256, 0, stream>>>(attnb, woT, bo, out, 4096,
                                                  2048, 2048);
}

// Round 5
// 307.635 us; speedup vs baseline: 1.1979x; 1.1979x over previous
//
#include <hip/hip_runtime.h>
#include <cstdint>

typedef __bf16 bf16;
typedef __attribute__((ext_vector_type(8))) __bf16 bf16x8;
typedef __attribute__((ext_vector_type(4))) __bf16 bf16x4;
typedef __attribute__((ext_vector_type(4))) float f32x4;

__device__ __forceinline__ void load_lds16(const void* g, void* l) {
  __builtin_amdgcn_global_load_lds(
      (const __attribute__((address_space(1))) unsigned int*)g,
      (__attribute__((address_space(3))) unsigned int*)l, 16, 0, 0);
}

__device__ __forceinline__ float fast_exp2(float x) {
  float r;
  asm volatile("v_exp_f32 %0, %1" : "=v"(r) : "v"(x));
  return r;
}

// ---------------------------------------------------------------------------
// GEMM: C[M,N] = A[M,K] @ Bt[N,K]^T (+bias). 128x128 tile, BK=64, 256 thr.
// ---------------------------------------------------------------------------
template <bool OUT_F32>
__global__ __launch_bounds__(256) void gemm_bt(
    const bf16* __restrict__ A, const bf16* __restrict__ Bt,
    const float* __restrict__ bias, void* __restrict__ Cv,
    int M, int N, int K) {
  __shared__ __align__(16) bf16 sA[128 * 64];
  __shared__ __align__(16) bf16 sB[128 * 64];
  const int t = threadIdx.x;
  const int w = t >> 6, lane = t & 63;
  const int quad = lane >> 4, l16 = lane & 15;
  const int wm = (w >> 1) * 64, wn = (w & 1) * 64;
  const int bm = blockIdx.y * 128, bn = blockIdx.x * 128;

  f32x4 acc[4][4] = {};
  const int srow = lane >> 3;
  const int sg = lane & 7;

  for (int kt = 0; kt < (K >> 6); ++kt) {
    const int k0 = kt << 6;
#pragma unroll
    for (int c2 = 0; c2 < 4; ++c2) {
      int c = c2 * 4 + w;
      int row = c * 8 + srow;
      int gg = sg ^ (row & 7);
      load_lds16(A + (int64_t)(bm + row) * K + k0 + gg * 8, sA + c * 512);
      load_lds16(Bt + (int64_t)(bn + row) * K + k0 + gg * 8, sB + c * 512);
    }
    asm volatile("s_waitcnt vmcnt(0)" ::: "memory");
    __syncthreads();
#pragma unroll
    for (int ks = 0; ks < 2; ++ks) {
      bf16x8 af[4], bfr[4];
#pragma unroll
      for (int i = 0; i < 4; ++i) {
        int m = wm + i * 16 + l16;
        af[i] = *(const bf16x8*)(sA + m * 64 + (((ks * 4 + quad) ^ (l16 & 7)) * 8));
        int n = wn + i * 16 + l16;
        bfr[i] = *(const bf16x8*)(sB + n * 64 + (((ks * 4 + quad) ^ (l16 & 7)) * 8));
      }
#pragma unroll
      for (int i = 0; i < 4; ++i)
#pragma unroll
        for (int j = 0; j < 4; ++j)
          acc[i][j] = __builtin_amdgcn_mfma_f32_16x16x32_bf16(af[i], bfr[j],
                                                              acc[i][j], 0, 0, 0);
    }
    __syncthreads();
  }
#pragma unroll
  for (int i = 0; i < 4; ++i) {
    int gm = bm + wm + i * 16 + quad * 4;
#pragma unroll
    for (int j = 0; j < 4; ++j) {
      int gn = bn + wn + j * 16 + l16;
      float bvv = bias ? bias[gn] : 0.0f;
#pragma unroll
      for (int r = 0; r < 4; ++r) {
        float v = acc[i][j][r] + bvv;
        if (OUT_F32)
          ((float*)Cv)[(int64_t)(gm + r) * N + gn] = v;
        else
          ((bf16*)Cv)[(int64_t)(gm + r) * N + gn] = (bf16)v;
      }
    }
  }
}

// ---------------------------------------------------------------------------
// Flash attention (causal GQA), mirror-paired q-tiles, TRANSPOSED scores.
// (R3 version — measured 81 µs.)  S^T = K·Q^T (in-lane softmax + 2 shuffles),
// P^T in separate sP (no post-QK^T barrier), O^T = V^T·P^T.
// Block = 4 waves; tiles A=p, B=31-p (64 q rows each); kv tiles of 64.
// ---------------------------------------------------------------------------
__global__ __launch_bounds__(256, 2) void attn(
    const bf16* __restrict__ QKV, const bf16* __restrict__ Vt,
    bf16* __restrict__ Out) {
  constexpr float CC = 0.08838834764831845f * 1.44269504088896f;  // scale*log2e
  __shared__ __align__(16) bf16 sK[2][64 * 128];
  __shared__ __align__(16) bf16 sV[2][128 * 64];
  __shared__ __align__(16) bf16 sP[128 * 64];  // [q_local][kv], 16B-swizzled

  const int t = threadIdx.x;
  const int w = t >> 6, lane = t & 63;
  const int quad = lane >> 4, l16 = lane & 15;
  const int p = blockIdx.x, h = blockIdx.y, b = blockIdx.z;
  const int g = h >> 2;
  const int wr0 = w * 16;
  const int kbase = 2048 + g * 128;
  const bf16* vtb = Vt + (int64_t)((b * 4 + g) * 128) * 2048;
  const int rk = lane >> 4, rv = lane >> 3, sgv = lane & 7;
  const int qrow0A = p * 64, qrow0B = (31 - p) * 64;
  const int niters = 32 - p;

  bf16x8 qreg[2][4];
#pragma unroll
  for (int u = 0; u < 2; ++u) {
    int qr = (u == 0 ? qrow0A : qrow0B);
#pragma unroll
    for (int ks = 0; ks < 4; ++ks)
      qreg[u][ks] = *(const bf16x8*)(QKV +
          (int64_t)(b * 2048 + qr + wr0 + l16) * 3072 + h * 128 + ks * 32 +
          quad * 8);
  }

  f32x4 oacc[2][8] = {};
  float mrow[2] = {-3.0e38f, -3.0e38f};
  float lrow[2] = {0.f, 0.f};

  auto stage = [&](int n0, bf16* sKb, bf16* sVb) {
#pragma unroll
    for (int c2 = 0; c2 < 4; ++c2) {
      int c = c2 * 4 + w;
      int rowk = c * 4 + rk;
      int ggk = (l16 & 8) | ((l16 ^ rowk) & 7);
      load_lds16(QKV + (int64_t)(b * 2048 + n0 + rowk) * 3072 + kbase + ggk * 8,
                 sKb + c * 512);
      int rowv = c * 8 + rv;
      int ggv = sgv ^ (rowv & 7);
      load_lds16(vtb + (int64_t)rowv * 2048 + n0 + ggv * 8, sVb + c * 512);
    }
  };

  stage(0, sK[0], sV[0]);

  const int prowA = wr0 + l16;
  const int prowB = 64 + wr0 + l16;

  for (int it = 0; it < niters; ++it) {
    const int cur = it & 1;
    const int n0 = it * 64;
    bf16* sKc = sK[cur];
    bf16* sVc = sV[cur];
    const bool actA = (it <= p);

    asm volatile("s_waitcnt vmcnt(0)\n\ts_barrier" ::: "memory");
    if (it + 1 < niters) stage(n0 + 64, sK[cur ^ 1], sV[cur ^ 1]);

    // ---- S^T = K Q^T : sacc[u][mj], row=kv=mj*16+quad*4+r, col=q=l16 ----
    f32x4 sacc[2][4] = {};
    if (actA) {
#pragma unroll
      for (int ks = 0; ks < 4; ++ks) {
        bf16x8 ak[4];
#pragma unroll
        for (int mj = 0; mj < 4; ++mj) {
          int kvr = mj * 16 + l16;
          int G = ks * 4 + quad;
          int slot = (G & 8) | ((G ^ kvr) & 7);
          ak[mj] = *(const bf16x8*)(sKc + kvr * 128 + slot * 8);
        }
#pragma unroll
        for (int mj = 0; mj < 4; ++mj) {
          sacc[0][mj] = __builtin_amdgcn_mfma_f32_16x16x32_bf16(
              ak[mj], qreg[0][ks], sacc[0][mj], 0, 0, 0);
          sacc[1][mj] = __builtin_amdgcn_mfma_f32_16x16x32_bf16(
              ak[mj], qreg[1][ks], sacc[1][mj], 0, 0, 0);
        }
      }
    } else {
#pragma unroll
      for (int ks = 0; ks < 4; ++ks) {
        bf16x8 ak[4];
#pragma unroll
        for (int mj = 0; mj < 4; ++mj) {
          int kvr = mj * 16 + l16;
          int G = ks * 4 + quad;
          int slot = (G & 8) | ((G ^ kvr) & 7);
          ak[mj] = *(const bf16x8*)(sKc + kvr * 128 + slot * 8);
        }
#pragma unroll
        for (int mj = 0; mj < 4; ++mj)
          sacc[1][mj] = __builtin_amdgcn_mfma_f32_16x16x32_bf16(
              ak[mj], qreg[1][ks], sacc[1][mj], 0, 0, 0);
      }
    }

    // ---- online softmax (raw scores; scale folded into CC) + P^T write ----
    auto softmax_u = [&](int u, bool last, int qrow0u, int prow) {
      if (last) {
        int q = qrow0u + wr0 + l16;
#pragma unroll
        for (int mj = 0; mj < 4; ++mj)
#pragma unroll
          for (int r = 0; r < 4; ++r) {
            int kv = n0 + mj * 16 + quad * 4 + r;
            if (kv > q) sacc[u][mj][r] = -3.0e38f;
          }
      }
      f32x4 m01, m23;
#pragma unroll
      for (int r = 0; r < 4; ++r) {
        m01[r] = fmaxf(sacc[u][0][r], sacc[u][1][r]);
        m23[r] = fmaxf(sacc[u][2][r], sacc[u][3][r]);
      }
      float mx = fmaxf(fmaxf(fmaxf(m01[0], m01[1]), fmaxf(m01[2], m01[3])),
                       fmaxf(fmaxf(m23[0], m23[1]), fmaxf(m23[2], m23[3])));
      mx = fmaxf(mx, __shfl_xor(mx, 16));
      mx = fmaxf(mx, __shfl_xor(mx, 32));
      float mnew = fmaxf(mrow[u], mx);
      float alpha = fast_exp2((mrow[u] - mnew) * CC);
      float rs = 0.f;
#pragma unroll
      for (int mj = 0; mj < 4; ++mj) {
        bf16x4 p4;
#pragma unroll
        for (int r = 0; r < 4; ++r) {
          float pv = fast_exp2((sacc[u][mj][r] - mnew) * CC);
          rs += pv;
          p4[r] = (bf16)pv;
        }
        int g16 = mj * 2 + (quad >> 1);
        int off = prow * 64 + ((g16 ^ (prow & 7)) * 8) + (quad & 1) * 4;
        *(bf16x4*)(sP + off) = p4;
      }
      rs += __shfl_xor(rs, 16);
      rs += __shfl_xor(rs, 32);
      lrow[u] = lrow[u] * alpha + rs;
      mrow[u] = mnew;
#pragma unroll
      for (int dj = 0; dj < 8; ++dj)
#pragma unroll
        for (int r = 0; r < 4; ++r) oacc[u][dj][r] *= alpha;
    };
    if (actA) softmax_u(0, it == p, qrow0A, prowA);
    softmax_u(1, it == niters - 1, qrow0B, prowB);

    asm volatile("s_waitcnt lgkmcnt(0)" ::: "memory");

    // ---- O^T += V^T P^T ----
#pragma unroll
    for (int ks2 = 0; ks2 < 2; ++ks2) {
      int G = ks2 * 4 + quad;
      bf16x8 bpA, bpB;
      if (actA)
        bpA = *(const bf16x8*)(sP + prowA * 64 + ((G ^ (prowA & 7)) * 8));
      bpB = *(const bf16x8*)(sP + prowB * 64 + ((G ^ (prowB & 7)) * 8));
      bf16x8 av[8];
#pragma unroll
      for (int dj = 0; dj < 8; ++dj) {
        int d = dj * 16 + l16;
        av[dj] = *(const bf16x8*)(sVc + d * 64 + ((G ^ (d & 7)) * 8));
      }
      if (actA) {
#pragma unroll
        for (int dj = 0; dj < 8; ++dj) {
          oacc[0][dj] = __builtin_amdgcn_mfma_f32_16x16x32_bf16(
              av[dj], bpA, oacc[0][dj], 0, 0, 0);
          oacc[1][dj] = __builtin_amdgcn_mfma_f32_16x16x32_bf16(
              av[dj], bpB, oacc[1][dj], 0, 0, 0);
        }
      } else {
#pragma unroll
        for (int dj = 0; dj < 8; ++dj)
          oacc[1][dj] = __builtin_amdgcn_mfma_f32_16x16x32_bf16(
              av[dj], bpB, oacc[1][dj], 0, 0, 0);
      }
    }
  }

  // ---- epilogue ----
#pragma unroll
  for (int u = 0; u < 2; ++u) {
    int qrow0u = (u == 0 ? qrow0A : qrow0B);
    float inv = 1.0f / lrow[u];
    int64_t grow = b * 2048 + qrow0u + wr0 + l16;
#pragma unroll
    for (int dj = 0; dj < 8; ++dj) {
      bf16x4 o4;
#pragma unroll
      for (int r = 0; r < 4; ++r) o4[r] = (bf16)(oacc[u][dj][r] * inv);
      *(bf16x4*)(Out + grow * 2048 + h * 128 + dj * 16 + quad * 4) = o4;
    }
  }
}

// ---------------------------------------------------------------------------
// Fused prep: convert_x (blocks 0..8191), transpose Wq/Wk/Wv/Wo (64x64 tiles),
// concat bias (last 12 blocks). One launch instead of six.
// ---------------------------------------------------------------------------
__device__ __forceinline__ void tr_tile(const float* __restrict__ W,
                                        bf16* __restrict__ Wt, int K, int N,
                                        int bx, int by, int t, float* tile) {
  int tx = t & 63, ty = t >> 6;
#pragma unroll
  for (int q2 = 0; q2 < 16; ++q2) {
    int r = ty + q2 * 4;
    tile[r * 65 + tx] = W[(int64_t)(by * 64 + r) * N + bx * 64 + tx];
  }
  __syncthreads();
#pragma unroll
  for (int q2 = 0; q2 < 16; ++q2) {
    int n = ty + q2 * 4;
    Wt[(int64_t)(bx * 64 + n) * K + by * 64 + tx] = (bf16)tile[tx * 65 + n];
  }
}

__global__ __launch_bounds__(256) void prep(
    const float* __restrict__ x, const float* __restrict__ Wq,
    const float* __restrict__ Wk, const float* __restrict__ Wv,
    const float* __restrict__ Wo, const float* __restrict__ bq,
    const float* __restrict__ bk, const float* __restrict__ bv,
    bf16* __restrict__ xb, bf16* __restrict__ wqkvT, bf16* __restrict__ woT,
    float* __restrict__ bqkv) {
  __shared__ float tile[64 * 65];
  const int bid = blockIdx.x;
  const int t = threadIdx.x;
  if (bid < 8192) {  // convert x -> bf16
    int idx = bid * 256 + t;
    float4 v = ((const float4*)x)[idx];
    bf16x4 o = {(bf16)v.x, (bf16)v.y, (bf16)v.z, (bf16)v.w};
    ((bf16x4*)xb)[idx] = o;
  } else if (bid < 8192 + 1024) {  // Wq
    int b2 = bid - 8192;
    tr_tile(Wq, wqkvT, 2048, 2048, b2 & 31, b2 >> 5, t, tile);
  } else if (bid < 8192 + 1024 + 256) {  // Wk
    int b2 = bid - (8192 + 1024);
    tr_tile(Wk, wqkvT + 2048 * 2048, 2048, 512, b2 & 7, b2 >> 3, t, tile);
  } else if (bid < 8192 + 1024 + 512) {  // Wv
    int b2 = bid - (8192 + 1024 + 256);
    tr_tile(Wv, wqkvT + 2560 * 2048, 2048, 512, b2 & 7, b2 >> 3, t, tile);
  } else if (bid < 8192 + 1024 + 512 + 1024) {  // Wo
    int b2 = bid - (8192 + 1024 + 512);
    tr_tile(Wo, woT, 2048, 2048, b2 & 31, b2 >> 5, t, tile);
  } else {  // bias concat (12 blocks)
    int i = (bid - (8192 + 1024 + 512 + 1024)) * 256 + t;
    if (i < 3072)
      bqkv[i] = i < 2048 ? bq[i] : (i < 2560 ? bk[i - 2048] : bv[i - 2560]);
  }
}

// V cols of QKV -> Vt [(b*4+g)*128 + d][2048]. grid (4, 64, 8), block (32,8)
__global__ void transpose_v(const bf16* __restrict__ QKV, bf16* __restrict__ Vt) {
  __shared__ bf16 tile[32][34];
  int dt = blockIdx.x, tt = blockIdx.y, bg = blockIdx.z;
  int b = bg >> 2, g = bg & 3;
  int tx = threadIdx.x, ty = threadIdx.y;
#pragma unroll
  for (int q2 = 0; q2 < 4; ++q2) {
    int trow = tt * 32 + ty + q2 * 8;
    tile[ty + q2 * 8][tx] =
        QKV[(int64_t)(b * 2048 + trow) * 3072 + 2560 + g * 128 + dt * 32 + tx];
  }
  __syncthreads();
#pragma unroll
  for (int q2 = 0; q2 < 4; ++q2) {
    int d = dt * 32 + ty + q2 * 8;
    Vt[(int64_t)(bg * 128 + d) * 2048 + tt * 32 + tx] = tile[tx][ty + q2 * 8];
  }
}

// ---------------------------------------------------------------------------
extern "C" void kernel_launch(void* const* d_in, const int* in_sizes, int n_in,
                              void* d_out, int out_size, void* d_ws,
                              size_t ws_size, hipStream_t stream) {
  const float* x = (const float*)d_in[0];
  const float* Wq = (const float*)d_in[1];
  const float* bq = (const float*)d_in[2];
  const float* Wk = (const float*)d_in[3];
  const float* bk = (const float*)d_in[4];
  const float* Wv = (const float*)d_in[5];
  const float* bv = (const float*)d_in[6];
  const float* Wo = (const float*)d_in[7];
  const float* bo = (const float*)d_in[8];
  float* out = (float*)d_out;

  char* ws = (char*)d_ws;
  bf16* xb = (bf16*)(ws);
  bf16* wqkvT = (bf16*)(ws + 16777216);
  bf16* woT = (bf16*)(ws + 29360128);
  float* bqkv = (float*)(ws + 37748736);
  bf16* qkv = (bf16*)(ws + 37761024);
  bf16* vt = (bf16*)(ws + 62926848);
  bf16* attnb = (bf16*)(ws + 67121152);

  prep<<<8192 + 1024 + 512 + 1024 + 12, 256, 0, stream>>>(
      x, Wq, Wk, Wv, Wo, bq, bk, bv, xb, wqkvT, woT, bqkv);

  // QKV = xb @ WqkvT^T + bqkv   [4096 x 3072]
  gemm_bt<false><<<dim3(24, 32), 256, 0, stream>>>(xb, wqkvT, bqkv, qkv, 4096,
                                                   3072, 2048);
  transpose_v<<<dim3(4, 64, 8), dim3(32, 8), 0, stream>>>(qkv, vt);
  attn<<<dim3(16, 16, 2), 256, 0, stream>>>(qkv, vt, attnb);
  // out = attnb @ WoT^T + bo    [4096 x 2048] fp32
  gemm_bt<true><<<dim3(16, 32), 256, 0, stream>>>(attnb, woT, bo, out, 4096,
                                                  2048, 2048);
}